// Round 11
// baseline (869.850 us; speedup 1.0000x reference)
//
#include <hip/hip_runtime.h>
#include <stdint.h>

#define GAS __attribute__((address_space(1)))
#define LAS __attribute__((address_space(3)))

typedef int v4i __attribute__((ext_vector_type(4)));

constexpr int Mdim = 8192;    // B*S = 4*2048
constexpr int Ndim = 16384;   // D_OUT
constexpr int Kdim = 4096;    // D_IN

__device__ __forceinline__ int pack4i8(int a, int b, int c, int d) {
    return (a & 255) | ((b & 255) << 8) | ((c & 255) << 16) | ((d & 255) << 24);
}

__device__ __forceinline__ int qz(float v, float inv) {
    return (int)fminf(fmaxf(rintf(v * inv), -128.0f), 127.0f);
}

// ---- pass 1: quantize x fp32 -> int8 (16 elems/thread) ----
__global__ void k_quant_x(const float* __restrict__ x, const float* __restrict__ asc,
                          int8_t* __restrict__ xq) {
    const int i = blockIdx.x * blockDim.x + threadIdx.x;
    const float inv = 1.0f / *asc;
    const float4* xv = (const float4*)x + (size_t)i * 4;
    float4 f0 = xv[0], f1 = xv[1], f2 = xv[2], f3 = xv[3];
    int4 o;
    o.x = pack4i8(qz(f0.x, inv), qz(f0.y, inv), qz(f0.z, inv), qz(f0.w, inv));
    o.y = pack4i8(qz(f1.x, inv), qz(f1.y, inv), qz(f1.z, inv), qz(f1.w, inv));
    o.z = pack4i8(qz(f2.x, inv), qz(f2.y, inv), qz(f2.z, inv), qz(f2.w, inv));
    o.w = pack4i8(qz(f3.x, inv), qz(f3.y, inv), qz(f3.z, inv), qz(f3.w, inv));
    ((int4*)xq)[i] = o;
}

// ---- pass 2: pack weights into FRAGMENT-LINEAR layout (verified round 9) ----
// chunk c = (ntile*64 + kstep)*64 + lane; lane l -> n = ntile*16 + (l&15),
// k = kstep*64 + (l>>4)*16. A wave's B-fragment = one contiguous 1 KB read.
__global__ void k_pack_w(const int* __restrict__ w, int8_t* __restrict__ wp) {
    const int c = blockIdx.x * blockDim.x + threadIdx.x;
    const int l = c & 63, ks = (c >> 6) & 63, nt = c >> 12;
    const int n = nt * 16 + (l & 15);
    const int k = (ks << 6) + ((l >> 4) << 4);
    const int4* src = (const int4*)(w + (size_t)n * Kdim + k);
    int4 a = src[0], b = src[1], cc = src[2], d = src[3];
    int4 o;
    o.x = pack4i8(a.x, a.y, a.z, a.w);
    o.y = pack4i8(b.x, b.y, b.z, b.w);
    o.z = pack4i8(cc.x, cc.y, cc.z, cc.w);
    o.w = pack4i8(d.x, d.y, d.z, d.w);
    ((int4*)wp)[c] = o;
}

// ============================================================================
// pass 3 (main): SUPER-STEP design. 256x256 tile, 8 waves (2M x 4N),
// wave tile 128x64. Barrier ONLY every 4 K-steps (16 per block):
//   - B: fragment-linear packed -> 4 coalesced 1KB loads/step straight to
//     registers (bP/bQ ping-pong, load-ahead-1). NEVER in LDS.
//   - A: cooperative LDS staging, super-buffer = 4 K-steps (64 KB), 2-deep
//     (128 KiB). Verified zero-conflict swizzle (rounds 2-10).
//   - inside a super-step waves FREE-RUN (per-wave deps only: compiler's
//     counted vmcnt for B regs, counted lgkm for A frags) -> waves drift,
//     one wave's reads/stages run under another's MFMA (m114 mechanism,
//     ~5200 cy windows). Per CU per K-step: MFMA 1306 cy/SIMD-pair vs
//     LDS 896 cy vs L2 ~860 cy -> MFMA-bound with slack on all side pipes.
//   - sync: per super-step tail: vmcnt(0) (retire own stages; B mostly
//     landed) ; s_barrier publishes buf^1. Hazard: buf^1 was last READ in
//     ss-1 (lgkm-complete before that barrier) -> safe to stage during ss.
// ============================================================================

#define KSTEP(BUF, KSL, T, BCUR, BNXT, ST, LB)                                 \
  {                                                                            \
    v4i afr[8];                                                                \
    _Pragma("unroll") for (int f = 0; f < 8; ++f)                              \
      afr[f] = *(const v4i*)(lds + (BUF) * 65536 + (KSL) * 16384 + arow + f * 1024); \
    if (ST) {                                                                  \
      int8_t* d = lds + ((BUF) ^ 1) * 65536 + (KSL) * 16384 + dstoff;          \
      const int8_t* s = rowA0 + ((T) + 4) * 64;                                \
      __builtin_amdgcn_global_load_lds((const GAS void*)s, (LAS void*)d, 16, 0, 0); \
      __builtin_amdgcn_global_load_lds((const GAS void*)(s + rb1off),          \
                                       (LAS void*)(d + 8192), 16, 0, 0);       \
    }                                                                          \
    if (LB) {                                                                  \
      _Pragma("unroll") for (int f = 0; f < 4; ++f)                            \
        BNXT[f] = *(const v4i*)(pB[f] + (((T) + 1) << 10));                    \
    }                                                                          \
    __builtin_amdgcn_s_setprio(1);                                             \
    _Pragma("unroll") for (int fi = 0; fi < 8; ++fi)                           \
      _Pragma("unroll") for (int fj = 0; fj < 4; ++fj)                         \
        acc[fi][fj] = __builtin_amdgcn_mfma_i32_16x16x64_i8(                   \
            afr[fi], BCUR[fj], acc[fi][fj], 0, 0, 0);                          \
    __builtin_amdgcn_s_setprio(0);                                             \
  }

#define SS_BARRIER                                                             \
  asm volatile("s_waitcnt vmcnt(0)" ::: "memory");                             \
  __builtin_amdgcn_s_barrier();                                                \
  __builtin_amdgcn_sched_barrier(0);

__global__ __launch_bounds__(512, 2)
void k_gemm_ss(const int8_t* __restrict__ Aq, const int8_t* __restrict__ Bp,
               const float* __restrict__ wscale, const float* __restrict__ asc,
               const float* __restrict__ bias, float* __restrict__ out) {
    __shared__ __align__(16) int8_t lds[131072];  // 2 superbufs x [4 ks][256 rows][64 B]
    const int tid = threadIdx.x, lane = tid & 63, w = tid >> 6;
    const int wm = w >> 2, wn = w & 3;              // 2M x 4N wave grid
    const int lrow = lane & 15, kgrp = lane >> 4;

    const int bid = blockIdx.x;                     // grid = 2048, %8 == 0
    const int swz = ((bid & 7) << 8) | (bid >> 3);  // bijective XCD swizzle
    const int mt = swz & 31, nt = swz >> 5;         // m fastest: B panel hot in L2
    const int m0 = mt << 8, n0 = nt << 8;

    // ---- A staging geometry (verified 0-conflict, rounds 2-10) ----
    const int srow = tid >> 2;                      // 0..127
    const int scol = (((tid & 3) ^ ((tid >> 3) & 3)) << 4);
    const int8_t* rowA0 = Aq + (size_t)(m0 + srow) * Kdim + scol;
    const size_t rb1off = (size_t)128 * Kdim;
    const int dstoff = w << 10;                     // + HW lane*16

    // ---- B packed fragment pointers: wave's 4 n-tiles ----
    const int ntb = (n0 >> 4) + (wn << 2);
    const int8_t* pB[4];
#pragma unroll
    for (int f = 0; f < 4; ++f)
        pB[f] = Bp + (((size_t)(ntb + f)) << 16) + (lane << 4);

    // ---- A read addressing (verified conflict-free swizzle) ----
    const int kc = (kgrp ^ ((lrow >> 1) & 3)) << 4;
    const int arow = ((wm << 7) + lrow) * 64 + kc;

    v4i acc[8][4];
#pragma unroll
    for (int i = 0; i < 8; ++i)
#pragma unroll
        for (int j = 0; j < 4; ++j) acc[i][j] = (v4i){0, 0, 0, 0};

    v4i bP[4], bQ[4];

    // prologue: stage superbuf 0 (tiles 0..3, 8 gloads/wave); load B(0); publish.
#pragma unroll
    for (int ks = 0; ks < 4; ++ks) {
        int8_t* d = lds + ks * 16384 + dstoff;
        const int8_t* s = rowA0 + ks * 64;
        __builtin_amdgcn_global_load_lds((const GAS void*)s, (LAS void*)d, 16, 0, 0);
        __builtin_amdgcn_global_load_lds((const GAS void*)(s + rb1off),
                                         (LAS void*)(d + 8192), 16, 0, 0);
    }
#pragma unroll
    for (int f = 0; f < 4; ++f) bP[f] = *(const v4i*)(pB[f]);
    SS_BARRIER

    // 7 double-super-steps (ss pairs 0&1 .. 12&13), static buf indices
    for (int p = 0; p < 7; ++p) {
        const int t0 = p << 3;
        KSTEP(0, 0, t0 + 0, bP, bQ, 1, 1)
        KSTEP(0, 1, t0 + 1, bQ, bP, 1, 1)
        KSTEP(0, 2, t0 + 2, bP, bQ, 1, 1)
        KSTEP(0, 3, t0 + 3, bQ, bP, 1, 1)
        SS_BARRIER
        KSTEP(1, 0, t0 + 4, bP, bQ, 1, 1)
        KSTEP(1, 1, t0 + 5, bQ, bP, 1, 1)
        KSTEP(1, 2, t0 + 6, bP, bQ, 1, 1)
        KSTEP(1, 3, t0 + 7, bQ, bP, 1, 1)
        SS_BARRIER
    }
    // ss = 14 (buf 0): stages tiles 60..63 into buf 1
    KSTEP(0, 0, 56, bP, bQ, 1, 1)
    KSTEP(0, 1, 57, bQ, bP, 1, 1)
    KSTEP(0, 2, 58, bP, bQ, 1, 1)
    KSTEP(0, 3, 59, bQ, bP, 1, 1)
    SS_BARRIER
    // ss = 15 (buf 1): tiles 60..63, no staging; B(64) doesn't exist
    KSTEP(1, 0, 60, bP, bQ, 0, 1)
    KSTEP(1, 1, 61, bQ, bP, 0, 1)
    KSTEP(1, 2, 62, bP, bQ, 0, 1)
    KSTEP(1, 3, 63, bQ, bP, 0, 0)

    // epilogue: y = i32 * (act_scale * wscale[n]) + bias[n]
    const float ascale = *asc;
#pragma unroll
    for (int fj = 0; fj < 4; ++fj) {
        const int col = n0 + (wn << 6) + fj * 16 + lrow;
        const float sc = ascale * wscale[col];
        const float bb = bias[col];
#pragma unroll
        for (int mi = 0; mi < 8; ++mi) {
            const int r0 = m0 + (wm << 7) + mi * 16 + (kgrp << 2);
            float* o = out + (size_t)r0 * Ndim + col;
#pragma unroll
            for (int q = 0; q < 4; ++q)
                o[(size_t)q * Ndim] = (float)acc[mi][fj][q] * sc + bb;
        }
    }
}

// ============================================================================
// fallback 128x128 kernel (only used if workspace is too small)
// ============================================================================
template <bool AQ>
__global__ __launch_bounds__(256)
void k_gemm(const int8_t* __restrict__ Aq, const float* __restrict__ Xf,
            const int* __restrict__ W32,
            const float* __restrict__ wscale, const float* __restrict__ asc,
            const float* __restrict__ bias, float* __restrict__ out) {
    constexpr int BM = 128, BN = 128, BK = 64;
    constexpr int KT = Kdim / BK;
    __shared__ __align__(16) int8_t As[2][BM * BK];
    __shared__ __align__(16) int8_t Bs[2][BN * BK];

    const int tid  = threadIdx.x;
    const int lane = tid & 63;
    const int wid  = tid >> 6;
    const int wm = wid >> 1, wn = wid & 1;
    const int lrow = lane & 15, kgrp = lane >> 4;

    const int cpx = gridDim.x >> 3;
    const int swz = ((int)blockIdx.x & 7) * cpx + ((int)blockIdx.x >> 3);
    const int mt = swz & (Mdim / BM - 1);
    const int nt = swz / (Mdim / BM);
    const int m0 = mt * BM, n0 = nt * BN;

    const float ascale = *asc;
    const float inv = 1.0f / ascale;

    v4i acc[4][4];
#pragma unroll
    for (int i = 0; i < 4; ++i)
#pragma unroll
        for (int j = 0; j < 4; ++j) acc[i][j] = (v4i){0, 0, 0, 0};

    auto stage = [&](int buf, int kt) {
        const int k0 = kt * BK;
        if constexpr (AQ) {
            int8_t* ldsp = &As[buf][wid << 10];
            const int8_t* g = Aq + (size_t)(m0 + (tid >> 2)) * Kdim + k0 + ((tid & 3) << 4);
            __builtin_amdgcn_global_load_lds((const GAS void*)g, (LAS void*)ldsp, 16, 0, 0);
            __builtin_amdgcn_global_load_lds((const GAS void*)(g + (size_t)64 * Kdim),
                                             (LAS void*)(ldsp + 4096), 16, 0, 0);
        } else {
            const int row = tid >> 1, cb = (tid & 1) << 5;
            const float4* src = (const float4*)(Xf + (size_t)(m0 + row) * Kdim + k0 + cb);
            int t[8];
#pragma unroll
            for (int j = 0; j < 8; ++j) {
                float4 f = src[j];
                t[j] = pack4i8(qz(f.x, inv), qz(f.y, inv), qz(f.z, inv), qz(f.w, inv));
            }
            int4* dst = (int4*)&As[buf][row * BK + cb];
            dst[0] = make_int4(t[0], t[1], t[2], t[3]);
            dst[1] = make_int4(t[4], t[5], t[6], t[7]);
        }
        {
            const int row = tid >> 1, cb = (tid & 1) << 5;
            const int4* src = (const int4*)(W32 + (size_t)(n0 + row) * Kdim + k0 + cb);
            int t[8];
#pragma unroll
            for (int j = 0; j < 8; ++j) {
                int4 vv = src[j];
                t[j] = pack4i8(vv.x, vv.y, vv.z, vv.w);
            }
            int4* dst = (int4*)&Bs[buf][row * BK + cb];
            dst[0] = make_int4(t[0], t[1], t[2], t[3]);
            dst[1] = make_int4(t[4], t[5], t[6], t[7]);
        }
    };

    stage(0, 0);
    for (int kt = 0; kt < KT; ++kt) {
        const int cur = kt & 1;
        __syncthreads();
        if (kt + 1 < KT) stage(cur ^ 1, kt + 1);

        v4i a[4], b[4];
        const int koff = kgrp << 4;
#pragma unroll
        for (int i = 0; i < 4; ++i) {
            a[i] = *(const v4i*)&As[cur][(wm * 64 + i * 16 + lrow) * BK + koff];
            b[i] = *(const v4i*)&Bs[cur][(wn * 64 + i * 16 + lrow) * BK + koff];
        }
#pragma unroll
        for (int i = 0; i < 4; ++i)
#pragma unroll
            for (int j = 0; j < 4; ++j)
                acc[i][j] = __builtin_amdgcn_mfma_i32_16x16x64_i8(a[i], b[j], acc[i][j], 0, 0, 0);
    }

#pragma unroll
    for (int j = 0; j < 4; ++j) {
        const int col = n0 + wn * 64 + j * 16 + lrow;
        const float sc = ascale * wscale[col];
        const float bb = bias[col];
#pragma unroll
        for (int i = 0; i < 4; ++i) {
            const int r0 = m0 + wm * 64 + i * 16 + (kgrp << 2);
            float* o = out + (size_t)r0 * Ndim + col;
#pragma unroll
            for (int r = 0; r < 4; ++r)
                o[(size_t)r * Ndim] = (float)acc[i][j][r] * sc + bb;
        }
    }
}

extern "C" void kernel_launch(void* const* d_in, const int* in_sizes, int n_in,
                              void* d_out, int out_size, void* d_ws, size_t ws_size,
                              hipStream_t stream) {
    const float* x      = (const float*)d_in[0];
    const int*   w32    = (const int*)d_in[1];   // int8 values sign-extended to int32
    const float* wscale = (const float*)d_in[2];
    const float* asc    = (const float*)d_in[3];
    const float* bias   = (const float*)d_in[4];
    float* out = (float*)d_out;

    const size_t nx = (size_t)Mdim * Kdim;  // 33,554,432 B for x_int8
    const size_t nw = (size_t)Ndim * Kdim;  // 67,108,864 B for packed w_int8
    int8_t* xq = (int8_t*)d_ws;
    int8_t* wp = xq + nx;

    const bool haveX = ws_size >= nx;
    const bool haveW = ws_size >= nx + nw;

    if (haveX) k_quant_x<<<(int)(nx / 16 / 256), 256, 0, stream>>>(x, asc, xq);
    if (haveW) k_pack_w<<<(int)(nw / 16 / 256), 256, 0, stream>>>(w32, wp);

    if (haveW) {
        dim3 grid((Mdim / 256) * (Ndim / 256));  // 2048
        k_gemm_ss<<<grid, 512, 0, stream>>>(xq, wp, wscale, asc, bias, out);
    } else if (haveX) {
        dim3 grid((Mdim / 128) * (Ndim / 128));  // 8192
        k_gemm<true><<<grid, 256, 0, stream>>>(xq, x, w32, wscale, asc, bias, out);
    } else {
        dim3 grid((Mdim / 128) * (Ndim / 128));
        k_gemm<false><<<grid, 256, 0, stream>>>(xq, x, w32, wscale, asc, bias, out);
    }
}

// Round 12
// 770.559 us; speedup vs baseline: 1.1289x; 1.1289x over previous
//
#include <hip/hip_runtime.h>
#include <stdint.h>

#define GAS __attribute__((address_space(1)))
#define LAS __attribute__((address_space(3)))

typedef int v4i  __attribute__((ext_vector_type(4)));
typedef int v16i __attribute__((ext_vector_type(16)));

constexpr int Mdim = 8192;    // B*S = 4*2048
constexpr int Ndim = 16384;   // D_OUT
constexpr int Kdim = 4096;    // D_IN

__device__ __forceinline__ int pack4i8(int a, int b, int c, int d) {
    return (a & 255) | ((b & 255) << 8) | ((c & 255) << 16) | ((d & 255) << 24);
}

__device__ __forceinline__ int qz(float v, float inv) {
    return (int)fminf(fmaxf(rintf(v * inv), -128.0f), 127.0f);
}

// ---- pass 1: quantize x fp32 -> int8 (16 elems/thread) ----
__global__ void k_quant_x(const float* __restrict__ x, const float* __restrict__ asc,
                          int8_t* __restrict__ xq) {
    const int i = blockIdx.x * blockDim.x + threadIdx.x;
    const float inv = 1.0f / *asc;
    const float4* xv = (const float4*)x + (size_t)i * 4;
    float4 f0 = xv[0], f1 = xv[1], f2 = xv[2], f3 = xv[3];
    int4 o;
    o.x = pack4i8(qz(f0.x, inv), qz(f0.y, inv), qz(f0.z, inv), qz(f0.w, inv));
    o.y = pack4i8(qz(f1.x, inv), qz(f1.y, inv), qz(f1.z, inv), qz(f1.w, inv));
    o.z = pack4i8(qz(f2.x, inv), qz(f2.y, inv), qz(f2.z, inv), qz(f2.w, inv));
    o.w = pack4i8(qz(f3.x, inv), qz(f3.y, inv), qz(f3.z, inv), qz(f3.w, inv));
    ((int4*)xq)[i] = o;
}

// ---- pass 2: weight int32 (sign-extended int8) -> packed int8 row-major ----
__global__ void k_conv_w(const int* __restrict__ w, int8_t* __restrict__ wq) {
    const int i = blockIdx.x * blockDim.x + threadIdx.x;
    const int4* wv = (const int4*)w + (size_t)i * 4;
    int4 a = wv[0], b = wv[1], c = wv[2], d = wv[3];
    int4 o;
    o.x = pack4i8(a.x, a.y, a.z, a.w);
    o.y = pack4i8(b.x, b.y, b.z, b.w);
    o.z = pack4i8(c.x, c.y, c.z, c.w);
    o.w = pack4i8(d.x, d.y, d.z, d.w);
    ((int4*)wq)[i] = o;
}

// ============================================================================
// pass 3 (main): 256x256 tile, 4 waves (2x2), 1 wave/SIMD, wave tile 128x128,
// mfma_i32_32x32x32_i8 (2x ops/instruction), acc[4][4] x 16 = 256 VGPR.
// LDS: A [2][256 rows][128 B] at 0 (64 KB), B same at 65536. 128 KiB total.
// K-tile = 128 int8. Per K-tile: 4 phases (ks=0..3) of {read next-ks frags
// (4 A + 4 B ds_read_b128, 8-slot XOR swizzle -> 4-way residual conflict);
// 16 MFMA on regs read last phase} -- per-wave ILP pipeline, reads drain
// under the wave's own 582-cy MFMA cluster (in-order issue: reads first).
// Sync (2 barriers + 1 vmcnt(0) per K-tile):
//   phase A(ks0): barrier2 (all waves consumed buf^1's old data -> safe to
//                 stage); stage(t+1 -> buf^1, 16 gloads); RD(ks1); MM(ks0)
//   phase B(ks1): RD(ks2); MM(ks1)
//   phase C(ks2): RD(ks3); MM(ks2)
//   phase D(ks3): vmcnt(0) (stage(t+1) issued 3 phases = ~1700 cy ago);
//                 barrier1; RD(t+1 ks0 from buf^1); MM(ks3)
// Fragment layouts (mirror of the end-to-end-verified 16x16x64 pattern):
//   A/B: row/col = lane&31, k-chunk = (lane>>5)*16 B.
//   C/D (verified m74/m101): col = lane&31, row = (reg&3)+8*(reg>>2)+4*(lane>>5).
// Swizzle: slot(ks) = ((ks*2 + lane>>5) ^ (lane&7)); staging source col
// pre-swizzled by the same involution (rule 21 both-sides).
// ============================================================================

#define VM0 asm volatile("s_waitcnt vmcnt(0)" ::: "memory")

#define RD(BUF, KS, AA, BB)                                                    \
  {                                                                            \
    _Pragma("unroll") for (int i_ = 0; i_ < 4; ++i_)                           \
      AA[i_] = *(const v4i*)(lds + (BUF) + arow + i_ * 4096 + kso[KS]);        \
    _Pragma("unroll") for (int i_ = 0; i_ < 4; ++i_)                           \
      BB[i_] = *(const v4i*)(lds + 65536 + (BUF) + brow + i_ * 4096 + kso[KS]);\
  }

#define MM(AA, BB)                                                             \
  {                                                                            \
    __builtin_amdgcn_s_setprio(1);                                             \
    _Pragma("unroll") for (int mi_ = 0; mi_ < 4; ++mi_)                        \
      _Pragma("unroll") for (int ni_ = 0; ni_ < 4; ++ni_)                      \
        acc[mi_][ni_] = __builtin_amdgcn_mfma_i32_32x32x32_i8(                 \
            AA[mi_], BB[ni_], acc[mi_][ni_], 0, 0, 0);                         \
    __builtin_amdgcn_s_setprio(0);                                             \
  }

// one K-tile. B0 = (t&1)<<15 (static). DOSTG: stage t+1. DORD: read t+1 ks0.
#define TILE(T, B0, DOSTG, DORD)                                               \
  {                                                                            \
    __builtin_amdgcn_s_barrier();                                              \
    __builtin_amdgcn_sched_barrier(0);                                         \
    if (DOSTG) stage((T) + 1);                                                 \
    RD(B0, 1, aQ, bQ)                                                          \
    MM(aP, bP)                                                                 \
    RD(B0, 2, aP, bP)                                                          \
    MM(aQ, bQ)                                                                 \
    RD(B0, 3, aQ, bQ)                                                          \
    MM(aP, bP)                                                                 \
    if (DORD) {                                                                \
      VM0;                                                                     \
      __builtin_amdgcn_s_barrier();                                            \
      __builtin_amdgcn_sched_barrier(0);                                       \
      RD((B0) ^ 32768, 0, aP, bP)                                              \
    }                                                                          \
    MM(aQ, bQ)                                                                 \
  }

__global__ __launch_bounds__(256, 1)
void k_gemm32(const int8_t* __restrict__ Aq, const int8_t* __restrict__ Bq,
              const float* __restrict__ wscale, const float* __restrict__ asc,
              const float* __restrict__ bias, float* __restrict__ out) {
    __shared__ __align__(16) int8_t lds[131072];
    const int tid = threadIdx.x, lane = tid & 63, w = tid >> 6;
    const int wm = w >> 1, wn = w & 1;              // 2M x 2N wave grid
    const int l5 = lane & 31, lhi = lane >> 5, llo = lane & 7;

    const int bid = blockIdx.x;                     // grid = 2048, %8 == 0
    const int swz = ((bid & 7) << 8) | (bid >> 3);  // bijective XCD swizzle
    const int mt = swz & 31, nt = swz >> 5;         // m fastest: share B panel
    const int m0 = mt << 8, n0 = nt << 8;

    // ---- staging: unit = 4 KB = 32 rows x 128 B; 8 A units + 8 B units
    // per K-tile. dest linear tid*16; source col inverse-swizzled.
    const int srow = tid >> 3;                      // 0..31 row in unit
    const int scol = (((tid & 7) ^ (srow & 7)) << 4);
    const int8_t* gA = Aq + (size_t)(m0 + srow) * Kdim + scol;
    const int8_t* gB = Bq + (size_t)(n0 + srow) * Kdim + scol;
    const size_t ustep = (size_t)32 * Kdim;
    const int dst0 = w << 10;                       // + unit*4096 + HW lane*16

    auto stage = [&](int t) {
        const int buf = (t & 1) << 15;
        const int kb = t << 7;
#pragma unroll
        for (int u = 0; u < 8; ++u)
            __builtin_amdgcn_global_load_lds((const GAS void*)(gA + u * ustep + kb),
                                             (LAS void*)(lds + buf + u * 4096 + dst0), 16, 0, 0);
#pragma unroll
        for (int u = 0; u < 8; ++u)
            __builtin_amdgcn_global_load_lds((const GAS void*)(gB + u * ustep + kb),
                                             (LAS void*)(lds + 65536 + buf + u * 4096 + dst0), 16, 0, 0);
    };

    // ---- fragment read addressing ----
    const int arow = (wm * 128 + l5) * 128;         // + mi*4096 + buf
    const int brow = (wn * 128 + l5) * 128;
    int kso[4];
#pragma unroll
    for (int ks = 0; ks < 4; ++ks) kso[ks] = (((ks * 2 + lhi) ^ llo) << 4);

    v16i acc[4][4];
#pragma unroll
    for (int i = 0; i < 4; ++i)
#pragma unroll
        for (int j = 0; j < 4; ++j)
#pragma unroll
            for (int r = 0; r < 16; ++r) acc[i][j][r] = 0;

    v4i aP[4], bP[4], aQ[4], bQ[4];

    // prologue: stage tile 0; drain; publish; preload ks0 frags.
    stage(0);
    VM0;
    __builtin_amdgcn_s_barrier();
    __builtin_amdgcn_sched_barrier(0);
    RD(0, 0, aP, bP)

    for (int tt = 0; tt < 15; ++tt) {
        const int t2 = tt * 2;
        TILE(t2,     0,     1, 1)
        TILE(t2 + 1, 32768, 1, 1)
    }
    TILE(30, 0,     1, 1)   // stages tile 31
    TILE(31, 32768, 0, 0)   // no stage, no next-read

    // epilogue: y = i32 * (act_scale * wscale[n]) + bias[n]
    // C/D: col = lane&31, row = (reg&3) + 8*(reg>>2) + 4*(lane>>5)
    const float ascale = *asc;
#pragma unroll
    for (int ni = 0; ni < 4; ++ni) {
        const int col = n0 + wn * 128 + ni * 32 + l5;
        const float sc = ascale * wscale[col];
        const float bb = bias[col];
#pragma unroll
        for (int mi = 0; mi < 4; ++mi) {
            const int rbase = m0 + wm * 128 + mi * 32 + 4 * lhi;
#pragma unroll
            for (int r = 0; r < 16; ++r) {
                const int row = rbase + (r & 3) + 8 * (r >> 2);
                out[(size_t)row * Ndim + col] = (float)acc[mi][ni][r] * sc + bb;
            }
        }
    }
}

// ============================================================================
// fallback 128x128 kernel (only used if workspace is too small)
// ============================================================================
template <bool AQ>
__global__ __launch_bounds__(256)
void k_gemm(const int8_t* __restrict__ Aq, const float* __restrict__ Xf,
            const int* __restrict__ W32,
            const float* __restrict__ wscale, const float* __restrict__ asc,
            const float* __restrict__ bias, float* __restrict__ out) {
    constexpr int BM = 128, BN = 128, BK = 64;
    constexpr int KT = Kdim / BK;
    __shared__ __align__(16) int8_t As[2][BM * BK];
    __shared__ __align__(16) int8_t Bs[2][BN * BK];

    const int tid  = threadIdx.x;
    const int lane = tid & 63;
    const int wid  = tid >> 6;
    const int wm = wid >> 1, wn = wid & 1;
    const int lrow = lane & 15, kgrp = lane >> 4;

    const int cpx = gridDim.x >> 3;
    const int swz = ((int)blockIdx.x & 7) * cpx + ((int)blockIdx.x >> 3);
    const int mt = swz & (Mdim / BM - 1);
    const int nt = swz / (Mdim / BM);
    const int m0 = mt * BM, n0 = nt * BN;

    const float ascale = *asc;
    const float inv = 1.0f / ascale;

    v4i acc[4][4];
#pragma unroll
    for (int i = 0; i < 4; ++i)
#pragma unroll
        for (int j = 0; j < 4; ++j) acc[i][j] = (v4i){0, 0, 0, 0};

    auto stg = [&](int buf, int kt) {
        const int k0 = kt * BK;
        if constexpr (AQ) {
            int8_t* ldsp = &As[buf][wid << 10];
            const int8_t* g = Aq + (size_t)(m0 + (tid >> 2)) * Kdim + k0 + ((tid & 3) << 4);
            __builtin_amdgcn_global_load_lds((const GAS void*)g, (LAS void*)ldsp, 16, 0, 0);
            __builtin_amdgcn_global_load_lds((const GAS void*)(g + (size_t)64 * Kdim),
                                             (LAS void*)(ldsp + 4096), 16, 0, 0);
        } else {
            const int row = tid >> 1, cb = (tid & 1) << 5;
            const float4* src = (const float4*)(Xf + (size_t)(m0 + row) * Kdim + k0 + cb);
            int t[8];
#pragma unroll
            for (int j = 0; j < 8; ++j) {
                float4 f = src[j];
                t[j] = pack4i8(qz(f.x, inv), qz(f.y, inv), qz(f.z, inv), qz(f.w, inv));
            }
            int4* dst = (int4*)&As[buf][row * BK + cb];
            dst[0] = make_int4(t[0], t[1], t[2], t[3]);
            dst[1] = make_int4(t[4], t[5], t[6], t[7]);
        }
        {
            const int row = tid >> 1, cb = (tid & 1) << 5;
            const int4* src = (const int4*)(W32 + (size_t)(n0 + row) * Kdim + k0 + cb);
            int t[8];
#pragma unroll
            for (int j = 0; j < 8; ++j) {
                int4 vv = src[j];
                t[j] = pack4i8(vv.x, vv.y, vv.z, vv.w);
            }
            int4* dst = (int4*)&Bs[buf][row * BK + cb];
            dst[0] = make_int4(t[0], t[1], t[2], t[3]);
            dst[1] = make_int4(t[4], t[5], t[6], t[7]);
        }
    };

    stg(0, 0);
    for (int kt = 0; kt < KT; ++kt) {
        const int cur = kt & 1;
        __syncthreads();
        if (kt + 1 < KT) stg(cur ^ 1, kt + 1);

        v4i a[4], b[4];
        const int koff = kgrp << 4;
#pragma unroll
        for (int i = 0; i < 4; ++i) {
            a[i] = *(const v4i*)&As[cur][(wm * 64 + i * 16 + lrow) * BK + koff];
            b[i] = *(const v4i*)&Bs[cur][(wn * 64 + i * 16 + lrow) * BK + koff];
        }
#pragma unroll
        for (int i = 0; i < 4; ++i)
#pragma unroll
            for (int j = 0; j < 4; ++j)
                acc[i][j] = __builtin_amdgcn_mfma_i32_16x16x64_i8(a[i], b[j], acc[i][j], 0, 0, 0);
    }

#pragma unroll
    for (int j = 0; j < 4; ++j) {
        const int col = n0 + wn * 64 + j * 16 + lrow;
        const float sc = ascale * wscale[col];
        const float bb = bias[col];
#pragma unroll
        for (int i = 0; i < 4; ++i) {
            const int r0 = m0 + wm * 64 + i * 16 + (kgrp << 2);
            float* o = out + (size_t)r0 * Ndim + col;
#pragma unroll
            for (int r = 0; r < 4; ++r)
                o[(size_t)r * Ndim] = (float)acc[i][j][r] * sc + bb;
        }
    }
}

extern "C" void kernel_launch(void* const* d_in, const int* in_sizes, int n_in,
                              void* d_out, int out_size, void* d_ws, size_t ws_size,
                              hipStream_t stream) {
    const float* x      = (const float*)d_in[0];
    const int*   w32    = (const int*)d_in[1];   // int8 values sign-extended to int32
    const float* wscale = (const float*)d_in[2];
    const float* asc    = (const float*)d_in[3];
    const float* bias   = (const float*)d_in[4];
    float* out = (float*)d_out;

    const size_t nx = (size_t)Mdim * Kdim;  // 33,554,432 B for x_int8
    const size_t nw = (size_t)Ndim * Kdim;  // 67,108,864 B for w_int8
    int8_t* xq = (int8_t*)d_ws;
    int8_t* wq = xq + nx;

    const bool haveX = ws_size >= nx;
    const bool haveW = ws_size >= nx + nw;

    if (haveX) k_quant_x<<<(int)(nx / 16 / 256), 256, 0, stream>>>(x, asc, xq);
    if (haveW) k_conv_w<<<(int)(nw / 16 / 256), 256, 0, stream>>>(w32, wq);

    if (haveW) {
        dim3 grid((Mdim / 256) * (Ndim / 256));  // 2048
        k_gemm32<<<grid, 256, 0, stream>>>(xq, wq, wscale, asc, bias, out);
    } else if (haveX) {
        dim3 grid((Mdim / 128) * (Ndim / 128));  // 8192
        k_gemm<true><<<grid, 256, 0, stream>>>(xq, x, w32, wscale, asc, bias, out);
    } else {
        dim3 grid((Mdim / 128) * (Ndim / 128));
        k_gemm<false><<<grid, 256, 0, stream>>>(xq, x, w32, wscale, asc, bias, out);
    }
}